// Round 1
// baseline (857.723 us; speedup 1.0000x reference)
//
#include <hip/hip_runtime.h>
#include <stdint.h>

#define B 64
#define P 8732
#define C 81
#define O 16
#define THRESH 0.5f
#define NEGPOS 3
#define VAR0 0.1f
#define VAR1 0.2f

// ---------------------------------------------------------------------------
// K0: zero-init workspace accumulators (ws is poisoned 0xAA before every call)
// ---------------------------------------------------------------------------
__global__ void init_k(unsigned long long* __restrict__ keys,
                       int* __restrict__ num_pos, float* __restrict__ possum,
                       float* __restrict__ acc) {
    int i = threadIdx.x;                    // 1024 threads
    if (i < B * O) keys[i] = 0ull;
    if (i < B) { num_pos[i] = 0; possum[i] = 0.f; }
    if (i < 2) acc[i] = 0.f;
}

// ---------------------------------------------------------------------------
// K1: per (b,p): IoU vs 16 truths -> best_truth_overlap/idx; per (b,o) argmax
// over p via packed atomicMax key = (float_bits(ov) << 32) | (~p)  -> ties
// resolve to the SMALLEST p, matching jnp.argmax first-occurrence.
// ---------------------------------------------------------------------------
__global__ void match_k(const float* __restrict__ dbox,
                        const float* __restrict__ truths,
                        float* __restrict__ bto, int* __restrict__ bti,
                        unsigned long long* __restrict__ keys) {
    __shared__ float st[O * 4];
    __shared__ unsigned long long skey[O];
    const int b = blockIdx.y;
    const int tid = threadIdx.x;
    const int p = blockIdx.x * blockDim.x + tid;
    if (tid < O * 4) st[tid] = truths[b * O * 4 + tid];
    if (tid < O) skey[tid] = 0ull;
    __syncthreads();
    if (p < P) {
        const float cx = dbox[p * 4 + 0], cy = dbox[p * 4 + 1];
        const float w  = dbox[p * 4 + 2], h  = dbox[p * 4 + 3];
        const float px0 = cx - w * 0.5f, py0 = cy - h * 0.5f;
        const float px1 = cx + w * 0.5f, py1 = cy + h * 0.5f;
        const float parea = (px1 - px0) * (py1 - py0);
        float best = -1.0f;
        int bidx = 0;
#pragma unroll
        for (int o = 0; o < O; ++o) {
            const float tx0 = st[o * 4 + 0], ty0 = st[o * 4 + 1];
            const float tx1 = st[o * 4 + 2], ty1 = st[o * 4 + 3];
            float ix = fminf(tx1, px1) - fmaxf(tx0, px0);
            float iy = fminf(ty1, py1) - fmaxf(ty0, py0);
            ix = fmaxf(ix, 0.f); iy = fmaxf(iy, 0.f);
            const float inter = ix * iy;
            const float ta = (tx1 - tx0) * (ty1 - ty0);
            const float ov = inter / (ta + parea - inter);   // denom > 0 always
            if (ov > best) { best = ov; bidx = o; }          // strict: first max wins
            const unsigned long long key =
                ((unsigned long long)__float_as_uint(ov) << 32) |
                (unsigned long long)(0xFFFFFFFFu - (unsigned)p);
            atomicMax(&skey[o], key);
        }
        bto[b * P + p] = best;
        bti[b * P + p] = bidx;
    }
    __syncthreads();
    if (tid < O) atomicMax(&keys[b * O + tid], skey[tid]);
}

// ---------------------------------------------------------------------------
// K2: force best-prior-per-truth: overlap=2.0, idx=o. Sequential per batch so
// duplicate prior indices resolve last-wins (numpy scatter semantics).
// ---------------------------------------------------------------------------
__global__ void force_k(const unsigned long long* __restrict__ keys,
                        float* __restrict__ bto, int* __restrict__ bti) {
    const int b = blockIdx.x * blockDim.x + threadIdx.x;
    if (b < B) {
        for (int o = 0; o < O; ++o) {
            const unsigned long long k = keys[b * O + o];
            const unsigned p = 0xFFFFFFFFu - (unsigned)(k & 0xFFFFFFFFull);
            bto[b * P + p] = 2.0f;
            bti[b * P + p] = o;
        }
    }
}

// ---------------------------------------------------------------------------
// K3: per (b,p): conf target, smooth-L1 loc loss (positives only), per-prior
// cross entropy; accumulate loss_l, per-row num_pos and positive-CE sum.
// ---------------------------------------------------------------------------
__global__ void loss_k(const float* __restrict__ loc_data,
                       const float* __restrict__ conf_data,
                       const float* __restrict__ dbox,
                       const float* __restrict__ truths,
                       const int* __restrict__ labels,
                       const float* __restrict__ bto, const int* __restrict__ bti,
                       float* __restrict__ ce, float* __restrict__ negce,
                       int* __restrict__ num_pos, float* __restrict__ possum,
                       float* __restrict__ acc) {
    const int b = blockIdx.y;
    const int tid = threadIdx.x;
    const int p = blockIdx.x * blockDim.x + tid;
    float l_contrib = 0.f, pce = 0.f;
    int np = 0;
    if (p < P) {
        const float ov = bto[b * P + p];
        const int t = bti[b * P + p];
        const int conf = (ov < THRESH) ? 0 : (labels[b * O + t] + 1);
        // cross entropy = logsumexp(row) - row[conf]
        const float* row = conf_data + ((size_t)b * P + p) * C;
        float m = row[0];
        for (int c = 1; c < C; ++c) m = fmaxf(m, row[c]);
        float s = 0.f;
        for (int c = 0; c < C; ++c) s += expf(row[c] - m);
        const float cev = (logf(s) + m) - row[conf];
        ce[b * P + p] = cev;
        const bool pos = conf > 0;
        negce[b * P + p] = pos ? 0.f : cev;
        if (pos) {
            np = 1;
            pce = cev;
            const float mx0 = truths[(b * O + t) * 4 + 0];
            const float my0 = truths[(b * O + t) * 4 + 1];
            const float mx1 = truths[(b * O + t) * 4 + 2];
            const float my1 = truths[(b * O + t) * 4 + 3];
            const float cx = dbox[p * 4 + 0], cy = dbox[p * 4 + 1];
            const float w  = dbox[p * 4 + 2], h  = dbox[p * 4 + 3];
            float tgt[4];
            tgt[0] = ((mx0 + mx1) * 0.5f - cx) / (VAR0 * w);
            tgt[1] = ((my0 + my1) * 0.5f - cy) / (VAR0 * h);
            tgt[2] = logf((mx1 - mx0) / w) / VAR1;
            tgt[3] = logf((my1 - my0) / h) / VAR1;
            const float* ld = loc_data + ((size_t)b * P + p) * 4;
#pragma unroll
            for (int j = 0; j < 4; ++j) {
                const float d = fabsf(ld[j] - tgt[j]);
                l_contrib += (d < 1.f) ? 0.5f * d * d : d - 0.5f;
            }
        }
    }
    __shared__ float sl[256];
    __shared__ float sp[256];
    __shared__ int sn[256];
    sl[tid] = l_contrib; sp[tid] = pce; sn[tid] = np;
    __syncthreads();
    for (int stp = 128; stp > 0; stp >>= 1) {
        if (tid < stp) {
            sl[tid] += sl[tid + stp];
            sp[tid] += sp[tid + stp];
            sn[tid] += sn[tid + stp];
        }
        __syncthreads();
    }
    if (tid == 0) {
        atomicAdd(&acc[0], sl[0]);
        atomicAdd(&possum[b], sp[0]);
        atomicAdd(&num_pos[b], sn[0]);
    }
}

// ---------------------------------------------------------------------------
// K4: per batch row, hard-negative mining: sum of top-k values of negce where
// k = min(3*num_pos, P). Binary search the k-th largest over float bits
// (values >= 0 so bits are order-monotone); tie-exact:
//   S = sum_{x > t} x + (k - cnt_{x > t}) * t
// ---------------------------------------------------------------------------
__global__ void mine_k(const float* __restrict__ negce,
                       const int* __restrict__ num_pos,
                       const float* __restrict__ possum,
                       float* __restrict__ acc) {
    const int b = blockIdx.x;
    const int tid = threadIdx.x;
    const float* x = negce + (size_t)b * P;
    int k = num_pos[b] * NEGPOS;
    if (k > P) k = P;
    __shared__ int scnt[256];
    __shared__ float ssum[256];
    __shared__ unsigned s_lo, s_hi;
    float S = 0.f;
    if (k > 0) {
        if (tid == 0) { s_lo = 0u; s_hi = 0x7F800000u; }
        __syncthreads();
        while (true) {
            const unsigned lo = s_lo, hi = s_hi;
            if (lo >= hi) break;
            const unsigned mid = lo + ((hi - lo) >> 1);
            const float t = __uint_as_float(mid);
            int cnt = 0;
            for (int i = tid; i < P; i += 256) cnt += (x[i] > t) ? 1 : 0;
            scnt[tid] = cnt;
            __syncthreads();
            for (int stp = 128; stp > 0; stp >>= 1) {
                if (tid < stp) scnt[tid] += scnt[tid + stp];
                __syncthreads();
            }
            if (tid == 0) {
                if (scnt[0] < k) s_hi = mid; else s_lo = mid + 1;
            }
            __syncthreads();
        }
        const float t = __uint_as_float(s_lo);   // k-th largest value
        float sum = 0.f;
        int cnt = 0;
        for (int i = tid; i < P; i += 256) {
            const float v = x[i];
            if (v > t) { sum += v; cnt++; }
        }
        ssum[tid] = sum; scnt[tid] = cnt;
        __syncthreads();
        for (int stp = 128; stp > 0; stp >>= 1) {
            if (tid < stp) { ssum[tid] += ssum[tid + stp]; scnt[tid] += scnt[tid + stp]; }
            __syncthreads();
        }
        S = ssum[0] + (float)(k - scnt[0]) * t;
    }
    if (tid == 0) atomicAdd(&acc[1], possum[b] + S);
}

// ---------------------------------------------------------------------------
// K5: finalize: N = sum num_pos; out = (loss_l/N, loss_c/N)
// ---------------------------------------------------------------------------
__global__ void final_k(const float* __restrict__ acc,
                        const int* __restrict__ num_pos,
                        float* __restrict__ out) {
    float N = 0.f;
    for (int b = 0; b < B; ++b) N += (float)num_pos[b];
    out[0] = acc[0] / N;
    out[1] = acc[1] / N;
}

extern "C" void kernel_launch(void* const* d_in, const int* in_sizes, int n_in,
                              void* d_out, int out_size, void* d_ws, size_t ws_size,
                              hipStream_t stream) {
    (void)in_sizes; (void)n_in; (void)out_size; (void)ws_size;
    const float* loc_data  = (const float*)d_in[0];   // [B,P,4]
    const float* conf_data = (const float*)d_in[1];   // [B,P,C]
    const float* dbox      = (const float*)d_in[2];   // [P,4] center-size
    const float* truths    = (const float*)d_in[3];   // [B,O,4] point form
    const int*   labels    = (const int*)d_in[4];     // [B,O]
    float* out = (float*)d_out;

    // workspace carve-up (~9 MB)
    unsigned long long* keys = (unsigned long long*)d_ws;       // B*O
    float* bto   = (float*)(keys + B * O);                      // B*P
    int*   bti   = (int*)(bto + (size_t)B * P);                 // B*P
    float* ce    = (float*)(bti + (size_t)B * P);               // B*P
    float* negce = ce + (size_t)B * P;                          // B*P
    int*   num_pos = (int*)(negce + (size_t)B * P);             // B
    float* possum  = (float*)(num_pos + B);                     // B
    float* acc     = possum + B;                                // [loss_l, loss_c]

    const dim3 grid2d((P + 255) / 256, B);

    init_k<<<1, 1024, 0, stream>>>(keys, num_pos, possum, acc);
    match_k<<<grid2d, 256, 0, stream>>>(dbox, truths, bto, bti, keys);
    force_k<<<1, 64, 0, stream>>>(keys, bto, bti);
    loss_k<<<grid2d, 256, 0, stream>>>(loc_data, conf_data, dbox, truths, labels,
                                       bto, bti, ce, negce, num_pos, possum, acc);
    mine_k<<<B, 256, 0, stream>>>(negce, num_pos, possum, acc);
    final_k<<<1, 1, 0, stream>>>(acc, num_pos, out);
}

// Round 2
// 578.715 us; speedup vs baseline: 1.4821x; 1.4821x over previous
//
#include <hip/hip_runtime.h>
#include <stdint.h>
#include <math.h>

#define B 64
#define P 8732
#define C 81
#define O 16
#define THRESH 0.5f
#define NEGPOS 3
#define VAR0 0.1f
#define VAR1 0.2f

// rows per wave in loss_k
#define RPW 8
// rows per block = 4 waves * RPW
#define RPB (4 * RPW)

// ---------------------------------------------------------------------------
// K0: zero-init workspace accumulators (ws is poisoned 0xAA before every call)
// ---------------------------------------------------------------------------
__global__ void init_k(unsigned long long* __restrict__ keys,
                       int* __restrict__ num_pos, float* __restrict__ possum,
                       float* __restrict__ lossl, float* __restrict__ acc) {
    int i = threadIdx.x;                    // 1024 threads
    if (i < B * O) keys[i] = 0ull;
    if (i < B) { num_pos[i] = 0; possum[i] = 0.f; lossl[i] = 0.f; }
    if (i < 2) acc[i] = 0.f;
}

// ---------------------------------------------------------------------------
// K1: per (b,p): IoU vs 16 truths -> best_truth_overlap/idx; per (b,o) argmax
// over p via packed atomicMax key = (float_bits(ov) << 32) | (~p)  -> ties
// resolve to the SMALLEST p, matching jnp.argmax first-occurrence.
// ---------------------------------------------------------------------------
__global__ void match_k(const float* __restrict__ dbox,
                        const float* __restrict__ truths,
                        float* __restrict__ bto, int* __restrict__ bti,
                        unsigned long long* __restrict__ keys) {
    __shared__ float st[O * 4];
    __shared__ unsigned long long skey[O];
    const int b = blockIdx.y;
    const int tid = threadIdx.x;
    const int p = blockIdx.x * blockDim.x + tid;
    if (tid < O * 4) st[tid] = truths[b * O * 4 + tid];
    if (tid < O) skey[tid] = 0ull;
    __syncthreads();
    if (p < P) {
        const float cx = dbox[p * 4 + 0], cy = dbox[p * 4 + 1];
        const float w  = dbox[p * 4 + 2], h  = dbox[p * 4 + 3];
        const float px0 = cx - w * 0.5f, py0 = cy - h * 0.5f;
        const float px1 = cx + w * 0.5f, py1 = cy + h * 0.5f;
        const float parea = (px1 - px0) * (py1 - py0);
        float best = -1.0f;
        int bidx = 0;
#pragma unroll
        for (int o = 0; o < O; ++o) {
            const float tx0 = st[o * 4 + 0], ty0 = st[o * 4 + 1];
            const float tx1 = st[o * 4 + 2], ty1 = st[o * 4 + 3];
            float ix = fminf(tx1, px1) - fmaxf(tx0, px0);
            float iy = fminf(ty1, py1) - fmaxf(ty0, py0);
            ix = fmaxf(ix, 0.f); iy = fmaxf(iy, 0.f);
            const float inter = ix * iy;
            const float ta = (tx1 - tx0) * (ty1 - ty0);
            const float ov = inter / (ta + parea - inter);   // denom > 0 always
            if (ov > best) { best = ov; bidx = o; }          // strict: first max wins
            const unsigned long long key =
                ((unsigned long long)__float_as_uint(ov) << 32) |
                (unsigned long long)(0xFFFFFFFFu - (unsigned)p);
            atomicMax(&skey[o], key);
        }
        bto[b * P + p] = best;
        bti[b * P + p] = bidx;
    }
    __syncthreads();
    if (tid < O) atomicMax(&keys[b * O + tid], skey[tid]);
}

// ---------------------------------------------------------------------------
// K2: force best-prior-per-truth: overlap=2.0, idx=o. Sequential per batch so
// duplicate prior indices resolve last-wins (numpy scatter semantics).
// ---------------------------------------------------------------------------
__global__ void force_k(const unsigned long long* __restrict__ keys,
                        float* __restrict__ bto, int* __restrict__ bti) {
    const int b = blockIdx.x * blockDim.x + threadIdx.x;
    if (b < B) {
        for (int o = 0; o < O; ++o) {
            const unsigned long long k = keys[b * O + o];
            const unsigned p = 0xFFFFFFFFu - (unsigned)(k & 0xFFFFFFFFull);
            bto[b * P + p] = 2.0f;
            bti[b * P + p] = o;
        }
    }
}

// ---------------------------------------------------------------------------
// K3: WAVE-PER-ROW cross entropy + smooth-L1. 64 lanes read the 81-float conf
// row coalesced into registers (v0 = row[lane], v1 = row[lane+64] for
// lane<17); shuffle-reduce max and sum(exp). Each conf cache line is read
// exactly once -> FETCH ~= 190 MB instead of 1.25 GB.
// ---------------------------------------------------------------------------
__global__ __launch_bounds__(256) void loss_k(
        const float* __restrict__ loc_data,
        const float* __restrict__ conf_data,
        const float* __restrict__ dbox,
        const float* __restrict__ truths,
        const int* __restrict__ labels,
        const float* __restrict__ bto, const int* __restrict__ bti,
        float* __restrict__ negce,
        int* __restrict__ num_pos, float* __restrict__ possum,
        float* __restrict__ lossl) {
    const int b = blockIdx.y;
    const int tid = threadIdx.x;
    const int lane = tid & 63;
    const int wid = tid >> 6;          // 0..3
    __shared__ float s_l, s_p;
    __shared__ int s_n;
    if (tid == 0) { s_l = 0.f; s_p = 0.f; s_n = 0; }
    __syncthreads();

    float l_lane = 0.f;                // lane-distributed smooth-L1 partials
    float p_acc = 0.f;                 // lane-0: positive-CE sum
    int n_acc = 0;                     // lane-0: positive count
    const int base = blockIdx.x * RPB + wid * RPW;

    for (int r = 0; r < RPW; ++r) {
        const int p = base + r;
        if (p >= P) break;
        const size_t row = (size_t)b * P + p;
        const float* rp = conf_data + row * C;
        // coalesced row load into registers
        const float v0 = rp[lane];
        const float v1 = (lane < C - 64) ? rp[lane + 64] : -INFINITY;
        // wave max
        float m = fmaxf(v0, v1);
        for (int off = 32; off; off >>= 1) m = fmaxf(m, __shfl_xor(m, off));
        // wave sum of exp
        float s = expf(v0 - m) + ((lane < C - 64) ? expf(v1 - m) : 0.f);
        for (int off = 32; off; off >>= 1) s += __shfl_xor(s, off);
        // conf target (uniform across wave)
        const float ov = bto[row];
        const int ti = bti[row];
        const int conf = (ov < THRESH) ? 0 : (labels[b * O + ti] + 1);
        const float pick = (conf < 64) ? __shfl(v0, conf) : __shfl(v1, conf - 64);
        const float cev = (logf(s) + m) - pick;
        const bool pos = conf > 0;
        if (lane == 0) negce[row] = pos ? 0.f : cev;
        // smooth-L1: lanes 0..3 each handle one box component
        if (pos && lane < 4) {
            const float mx0 = truths[(b * O + ti) * 4 + 0];
            const float my0 = truths[(b * O + ti) * 4 + 1];
            const float mx1 = truths[(b * O + ti) * 4 + 2];
            const float my1 = truths[(b * O + ti) * 4 + 3];
            const float cx = dbox[p * 4 + 0], cy = dbox[p * 4 + 1];
            const float w  = dbox[p * 4 + 2], h  = dbox[p * 4 + 3];
            const float t0 = ((mx0 + mx1) * 0.5f - cx) / (VAR0 * w);
            const float t1 = ((my0 + my1) * 0.5f - cy) / (VAR0 * h);
            const float t2 = logf((mx1 - mx0) / w) / VAR1;
            const float t3 = logf((my1 - my0) / h) / VAR1;
            const float tgt = (lane == 0) ? t0 : (lane == 1) ? t1
                             : (lane == 2) ? t2 : t3;
            const float d = fabsf(loc_data[row * 4 + lane] - tgt);
            l_lane += (d < 1.f) ? 0.5f * d * d : d - 0.5f;
        }
        if (lane == 0 && pos) { p_acc += cev; n_acc++; }
    }
    // reduce lane-distributed loc loss once
    for (int off = 32; off; off >>= 1) l_lane += __shfl_xor(l_lane, off);
    if (lane == 0) {
        atomicAdd(&s_l, l_lane);
        atomicAdd(&s_p, p_acc);
        atomicAdd(&s_n, n_acc);
    }
    __syncthreads();
    if (tid == 0) {
        atomicAdd(&lossl[b], s_l);
        atomicAdd(&possum[b], s_p);
        atomicAdd(&num_pos[b], s_n);
    }
}

// ---------------------------------------------------------------------------
// K4: hard-negative mining, values held in REGISTERS (1024 thr x 9 regs).
// Binary search the k-th largest over float bits; each iteration is an
// in-register count + shuffle reduce + one barrier (double-buffered LDS).
//   S = sum_{x > t} x + (k - cnt_{x > t}) * t   (tie-exact)
// ---------------------------------------------------------------------------
__global__ __launch_bounds__(1024) void mine_k(
        const float* __restrict__ negce,
        const int* __restrict__ num_pos,
        const float* __restrict__ possum,
        float* __restrict__ acc) {
    const int b = blockIdx.x;
    const int tid = threadIdx.x;
    const int lane = tid & 63;
    const int wid = tid >> 6;          // 0..15
    const float* x = negce + (size_t)b * P;
    float v[9];
#pragma unroll
    for (int j = 0; j < 9; ++j) {
        const int i = tid + j * 1024;
        v[j] = (i < P) ? x[i] : -1.0f;   // pad below any threshold (t >= 0)
    }
    int k = num_pos[b] * NEGPOS;
    if (k > P) k = P;

    __shared__ int wred[2][16];
    __shared__ float wsumf[16];
    __shared__ int wcnt[16];
    float S = 0.f;
    if (k > 0) {
        unsigned lo = 0u, hi = 0x7F800000u;   // block-uniform in registers
        int parity = 0;
        while (lo < hi) {
            const unsigned mid = lo + ((hi - lo) >> 1);
            const float t = __uint_as_float(mid);
            int cnt = 0;
#pragma unroll
            for (int j = 0; j < 9; ++j) cnt += (v[j] > t) ? 1 : 0;
            for (int off = 32; off; off >>= 1) cnt += __shfl_xor(cnt, off);
            if (lane == 0) wred[parity][wid] = cnt;
            __syncthreads();
            int total = 0;
#pragma unroll
            for (int w = 0; w < 16; ++w) total += wred[parity][w];
            if (total < k) hi = mid; else lo = mid + 1;   // uniform branch
            parity ^= 1;
        }
        const float t = __uint_as_float(lo);  // k-th largest value
        float sum = 0.f;
        int cnt = 0;
#pragma unroll
        for (int j = 0; j < 9; ++j) {
            if (v[j] > t) { sum += v[j]; cnt++; }
        }
        for (int off = 32; off; off >>= 1) {
            sum += __shfl_xor(sum, off);
            cnt += __shfl_xor(cnt, off);
        }
        if (lane == 0) { wsumf[wid] = sum; wcnt[wid] = cnt; }
        __syncthreads();
        if (tid == 0) {
            float ts = 0.f; int tc = 0;
#pragma unroll
            for (int w = 0; w < 16; ++w) { ts += wsumf[w]; tc += wcnt[w]; }
            S = ts + (float)(k - tc) * t;
        }
    }
    if (tid == 0) atomicAdd(&acc[1], possum[b] + S);
}

// ---------------------------------------------------------------------------
// K5: finalize: N = sum num_pos; out = (sum lossl / N, loss_c / N)
// ---------------------------------------------------------------------------
__global__ void final_k(const float* __restrict__ acc,
                        const int* __restrict__ num_pos,
                        const float* __restrict__ lossl,
                        float* __restrict__ out) {
    float N = 0.f, L = 0.f;
    for (int b = 0; b < B; ++b) { N += (float)num_pos[b]; L += lossl[b]; }
    out[0] = L / N;
    out[1] = acc[1] / N;
}

extern "C" void kernel_launch(void* const* d_in, const int* in_sizes, int n_in,
                              void* d_out, int out_size, void* d_ws, size_t ws_size,
                              hipStream_t stream) {
    (void)in_sizes; (void)n_in; (void)out_size; (void)ws_size;
    const float* loc_data  = (const float*)d_in[0];   // [B,P,4]
    const float* conf_data = (const float*)d_in[1];   // [B,P,C]
    const float* dbox      = (const float*)d_in[2];   // [P,4] center-size
    const float* truths    = (const float*)d_in[3];   // [B,O,4] point form
    const int*   labels    = (const int*)d_in[4];     // [B,O]
    float* out = (float*)d_out;

    // workspace carve-up (~7 MB)
    unsigned long long* keys = (unsigned long long*)d_ws;       // B*O
    float* bto   = (float*)(keys + B * O);                      // B*P
    int*   bti   = (int*)(bto + (size_t)B * P);                 // B*P
    float* negce = (float*)(bti + (size_t)B * P);               // B*P
    int*   num_pos = (int*)(negce + (size_t)B * P);             // B
    float* possum  = (float*)(num_pos + B);                     // B
    float* lossl   = possum + B;                                // B
    float* acc     = lossl + B;                                 // [_, loss_c]

    init_k<<<1, 1024, 0, stream>>>(keys, num_pos, possum, lossl, acc);
    match_k<<<dim3((P + 255) / 256, B), 256, 0, stream>>>(dbox, truths, bto, bti, keys);
    force_k<<<1, 64, 0, stream>>>(keys, bto, bti);
    loss_k<<<dim3((P + RPB - 1) / RPB, B), 256, 0, stream>>>(
        loc_data, conf_data, dbox, truths, labels, bto, bti,
        negce, num_pos, possum, lossl);
    mine_k<<<B, 1024, 0, stream>>>(negce, num_pos, possum, acc);
    final_k<<<1, 1, 0, stream>>>(acc, num_pos, lossl, out);
}

// Round 3
// 379.750 us; speedup vs baseline: 2.2587x; 1.5239x over previous
//
#include <hip/hip_runtime.h>
#include <stdint.h>
#include <math.h>

#define B 64
#define P 8732
#define C 81
#define O 16
#define THRESH 0.5f
#define NEGPOS 3
#define VAR0 0.1f
#define VAR1 0.2f

// loss_k tiling: 4 waves/block, 4 rows per wave-iteration (16-lane groups)
#define ITER 8
#define ROWS_PER_WAVE (4 * ITER)          // 32
#define ROWS_PER_BLOCK (4 * ROWS_PER_WAVE) // 128

// ---------------------------------------------------------------------------
// K0: zero-init accumulators (ws is poisoned 0xAA before every call)
// ---------------------------------------------------------------------------
__global__ void init_k(int* __restrict__ num_pos, float* __restrict__ possum,
                       float* __restrict__ lossl, float* __restrict__ acc) {
    int i = threadIdx.x;
    if (i < B) { num_pos[i] = 0; possum[i] = 0.f; lossl[i] = 0.f; }
    if (i < 2) acc[i] = 0.f;
}

// ---------------------------------------------------------------------------
// K1: best prior per (b,o). One wave per (b,o): lane-strided scan over P with
// packed running max key = (float_bits(ov) << 32) | ~p  -> ties resolve to the
// SMALLEST p (jnp.argmax first-occurrence). No atomics. Lane 0 writes the
// forced-prior index directly.
// ---------------------------------------------------------------------------
__global__ __launch_bounds__(1024) void bp_k(const float* __restrict__ dbox,
                                             const float* __restrict__ truths,
                                             int* __restrict__ forced_p) {
    const int b = blockIdx.x;
    const int tid = threadIdx.x;
    const int lane = tid & 63;
    const int o = tid >> 6;               // 0..15
    const float tx0 = truths[(b * O + o) * 4 + 0];
    const float ty0 = truths[(b * O + o) * 4 + 1];
    const float tx1 = truths[(b * O + o) * 4 + 2];
    const float ty1 = truths[(b * O + o) * 4 + 3];
    const float ta = (tx1 - tx0) * (ty1 - ty0);

    unsigned long long best = 0ull;
    for (int p = lane; p < P; p += 64) {
        const float4 db = *(const float4*)(dbox + (size_t)p * 4);
        const float px0 = db.x - db.z * 0.5f, py0 = db.y - db.w * 0.5f;
        const float px1 = db.x + db.z * 0.5f, py1 = db.y + db.w * 0.5f;
        const float parea = (px1 - px0) * (py1 - py0);
        float ix = fminf(tx1, px1) - fmaxf(tx0, px0);
        float iy = fminf(ty1, py1) - fmaxf(ty0, py0);
        ix = fmaxf(ix, 0.f); iy = fmaxf(iy, 0.f);
        const float inter = ix * iy;
        const float ov = inter / (ta + parea - inter);
        const unsigned long long key =
            ((unsigned long long)__float_as_uint(ov) << 32) |
            (unsigned long long)(0xFFFFFFFFu - (unsigned)p);
        if (key > best) best = key;
    }
    for (int off = 32; off; off >>= 1) {
        const unsigned long long o2 = __shfl_xor(best, off);
        if (o2 > best) best = o2;
    }
    if (lane == 0)
        forced_p[b * O + o] = (int)(0xFFFFFFFFu - (unsigned)(best & 0xFFFFFFFFull));
}

// ---------------------------------------------------------------------------
// K2: fused match + CE + smooth-L1. 16-lane groups, 4 rows per wave at once:
//  - lane o=sub computes IoU(truth_o, prior_p) -> depth-4 pair argmax
//  - forced override via 16-entry forced_p list + ballot (highest o = last-wins)
//  - CE: 6 strided register loads per lane, depth-4 max / sum+pick reduces
// All shuffles are shared across the wave's 4 groups (4-way ILP).
// ---------------------------------------------------------------------------
__global__ __launch_bounds__(256) void loss_k(
        const float* __restrict__ loc_data,
        const float* __restrict__ conf_data,
        const float* __restrict__ dbox,
        const float* __restrict__ truths,
        const int* __restrict__ labels,
        const int* __restrict__ forced_p,
        float* __restrict__ negce,
        int* __restrict__ num_pos, float* __restrict__ possum,
        float* __restrict__ lossl) {
    const int b = blockIdx.y;
    const int tid = threadIdx.x;
    const int lane = tid & 63;
    const int wid = tid >> 6;             // 0..3
    const int sub = lane & 15;
    const int g = lane >> 4;              // group 0..3

    __shared__ float s_truth[O * 4];
    __shared__ int s_fp[O];
    __shared__ int s_lab[O];
    __shared__ float s_l, s_p;
    __shared__ int s_n;
    if (tid < O * 4) s_truth[tid] = truths[b * O * 4 + tid];
    if (tid < O) { s_fp[tid] = forced_p[b * O + tid]; s_lab[tid] = labels[b * O + tid]; }
    if (tid == 0) { s_l = 0.f; s_p = 0.f; s_n = 0; }
    __syncthreads();

    // this lane's truth (o = sub)
    const float tx0 = s_truth[sub * 4 + 0], ty0 = s_truth[sub * 4 + 1];
    const float tx1 = s_truth[sub * 4 + 2], ty1 = s_truth[sub * 4 + 3];
    const float tarea = (tx1 - tx0) * (ty1 - ty0);
    const int myfp = s_fp[sub];

    float l_acc = 0.f;      // smooth-L1 partials (lanes sub<4)
    float p_acc = 0.f;      // positive-CE partial (lanes sub==0)
    int n_acc = 0;          // positive count partial (lanes sub==0)

    const int wbase = blockIdx.x * ROWS_PER_BLOCK + wid * ROWS_PER_WAVE;

    for (int r = 0; r < ITER; ++r) {
        const int p = wbase + 4 * r + g;
        const bool active = (p < P);
        const int pc = active ? p : P - 1;      // clamp for safe loads
        const size_t row = (size_t)b * P + pc;

        // ---- prior box (broadcast within group)
        const float4 db = *(const float4*)(dbox + (size_t)pc * 4);
        const float cx = db.x, cy = db.y, w = db.z, h = db.w;
        const float px0 = cx - w * 0.5f, py0 = cy - h * 0.5f;
        const float px1 = cx + w * 0.5f, py1 = cy + h * 0.5f;
        const float parea = (px1 - px0) * (py1 - py0);

        // ---- IoU with truth `sub`, group argmax (first max = smallest o)
        float ix = fminf(tx1, px1) - fmaxf(tx0, px0);
        float iy = fminf(ty1, py1) - fmaxf(ty0, py0);
        ix = fmaxf(ix, 0.f); iy = fmaxf(iy, 0.f);
        const float inter = ix * iy;
        float ov = inter / (tarea + parea - inter);
        int ti = sub;
        for (int off = 8; off; off >>= 1) {
            const float o2 = __shfl_xor(ov, off);
            const int i2 = __shfl_xor(ti, off);
            if (o2 > ov || (o2 == ov && i2 < ti)) { ov = o2; ti = i2; }
        }
        // ---- forced override (scatter-with-last-wins semantics)
        const unsigned long long bal = __ballot(active && (myfp == pc));
        const unsigned mask16 = (unsigned)((bal >> (16 * g)) & 0xFFFFull);
        if (mask16 != 0u) { ti = 31 - __clz(mask16); ov = 2.0f; }
        const int conf = (ov < THRESH) ? 0 : (s_lab[ti] + 1);
        const bool pos = conf > 0;

        // ---- CE: strided register loads (coalesced 64B segments per group)
        const float* rp = conf_data + row * C;
        float v[6];
#pragma unroll
        for (int j = 0; j < 5; ++j) v[j] = rp[sub + 16 * j];
        const float v80 = rp[80];
        v[5] = (sub == 0) ? v80 : -INFINITY;

        float m = v[0];
#pragma unroll
        for (int j = 1; j < 6; ++j) m = fmaxf(m, v[j]);
        for (int off = 8; off; off >>= 1) m = fmaxf(m, __shfl_xor(m, off));

        float s = 0.f, pk = 0.f;
#pragma unroll
        for (int j = 0; j < 5; ++j) {
            s += expf(v[j] - m);
            pk += (sub + 16 * j == conf) ? v[j] : 0.f;
        }
        s += expf(v[5] - m);                      // 0 for sub!=0
        if (sub == 0 && conf == 80) pk = v80;
        for (int off = 8; off; off >>= 1) {
            s += __shfl_xor(s, off);
            pk += __shfl_xor(pk, off);
        }
        const float cev = (logf(s) + m) - pk;

        if (active && sub == 0) {
            negce[row] = pos ? 0.f : cev;
            if (pos) { p_acc += cev; n_acc++; }
        }
        // ---- smooth-L1: lanes sub<4 handle one component each
        if (active && pos && sub < 4) {
            const float mx0 = s_truth[ti * 4 + 0];
            const float my0 = s_truth[ti * 4 + 1];
            const float mx1 = s_truth[ti * 4 + 2];
            const float my1 = s_truth[ti * 4 + 3];
            float tgt;
            if (sub == 0)      tgt = ((mx0 + mx1) * 0.5f - cx) / (VAR0 * w);
            else if (sub == 1) tgt = ((my0 + my1) * 0.5f - cy) / (VAR0 * h);
            else if (sub == 2) tgt = logf((mx1 - mx0) / w) / VAR1;
            else               tgt = logf((my1 - my0) / h) / VAR1;
            const float d = fabsf(loc_data[row * 4 + sub] - tgt);
            l_acc += (d < 1.f) ? 0.5f * d * d : d - 0.5f;
        }
    }
    // wave reduction of partials, then block, then global
    for (int off = 32; off; off >>= 1) {
        l_acc += __shfl_xor(l_acc, off);
        p_acc += __shfl_xor(p_acc, off);
        n_acc += __shfl_xor(n_acc, off);
    }
    if (lane == 0) {
        atomicAdd(&s_l, l_acc);
        atomicAdd(&s_p, p_acc);
        atomicAdd(&s_n, n_acc);
    }
    __syncthreads();
    if (tid == 0) {
        atomicAdd(&lossl[b], s_l);
        atomicAdd(&possum[b], s_p);
        atomicAdd(&num_pos[b], s_n);
    }
}

// ---------------------------------------------------------------------------
// K3: hard-negative mining, row in registers (1024 thr x 9 regs); binary
// search k-th largest over float bits; tie-exact sum.
// ---------------------------------------------------------------------------
__global__ __launch_bounds__(1024) void mine_k(
        const float* __restrict__ negce,
        const int* __restrict__ num_pos,
        const float* __restrict__ possum,
        float* __restrict__ acc) {
    const int b = blockIdx.x;
    const int tid = threadIdx.x;
    const int lane = tid & 63;
    const int wid = tid >> 6;          // 0..15
    const float* x = negce + (size_t)b * P;
    float v[9];
#pragma unroll
    for (int j = 0; j < 9; ++j) {
        const int i = tid + j * 1024;
        v[j] = (i < P) ? x[i] : -1.0f;
    }
    int k = num_pos[b] * NEGPOS;
    if (k > P) k = P;

    __shared__ int wred[2][16];
    __shared__ float wsumf[16];
    __shared__ int wcnt[16];
    float S = 0.f;
    if (k > 0) {
        unsigned lo = 0u, hi = 0x7F800000u;
        int parity = 0;
        while (lo < hi) {
            const unsigned mid = lo + ((hi - lo) >> 1);
            const float t = __uint_as_float(mid);
            int cnt = 0;
#pragma unroll
            for (int j = 0; j < 9; ++j) cnt += (v[j] > t) ? 1 : 0;
            for (int off = 32; off; off >>= 1) cnt += __shfl_xor(cnt, off);
            if (lane == 0) wred[parity][wid] = cnt;
            __syncthreads();
            int total = 0;
#pragma unroll
            for (int w = 0; w < 16; ++w) total += wred[parity][w];
            if (total < k) hi = mid; else lo = mid + 1;
            parity ^= 1;
        }
        const float t = __uint_as_float(lo);
        float sum = 0.f;
        int cnt = 0;
#pragma unroll
        for (int j = 0; j < 9; ++j) {
            if (v[j] > t) { sum += v[j]; cnt++; }
        }
        for (int off = 32; off; off >>= 1) {
            sum += __shfl_xor(sum, off);
            cnt += __shfl_xor(cnt, off);
        }
        if (lane == 0) { wsumf[wid] = sum; wcnt[wid] = cnt; }
        __syncthreads();
        if (tid == 0) {
            float ts = 0.f; int tc = 0;
#pragma unroll
            for (int w = 0; w < 16; ++w) { ts += wsumf[w]; tc += wcnt[w]; }
            S = ts + (float)(k - tc) * t;
        }
    }
    if (tid == 0) atomicAdd(&acc[1], possum[b] + S);
}

// ---------------------------------------------------------------------------
// K4: finalize
// ---------------------------------------------------------------------------
__global__ void final_k(const float* __restrict__ acc,
                        const int* __restrict__ num_pos,
                        const float* __restrict__ lossl,
                        float* __restrict__ out) {
    float N = 0.f, L = 0.f;
    for (int b = 0; b < B; ++b) { N += (float)num_pos[b]; L += lossl[b]; }
    out[0] = L / N;
    out[1] = acc[1] / N;
}

extern "C" void kernel_launch(void* const* d_in, const int* in_sizes, int n_in,
                              void* d_out, int out_size, void* d_ws, size_t ws_size,
                              hipStream_t stream) {
    (void)in_sizes; (void)n_in; (void)out_size; (void)ws_size;
    const float* loc_data  = (const float*)d_in[0];   // [B,P,4]
    const float* conf_data = (const float*)d_in[1];   // [B,P,C]
    const float* dbox      = (const float*)d_in[2];   // [P,4] center-size
    const float* truths    = (const float*)d_in[3];   // [B,O,4] point form
    const int*   labels    = (const int*)d_in[4];     // [B,O]
    float* out = (float*)d_out;

    // workspace carve-up (~2.3 MB)
    int* forced_p = (int*)d_ws;                                 // B*O
    float* negce  = (float*)(forced_p + B * O);                 // B*P
    int* num_pos  = (int*)(negce + (size_t)B * P);              // B
    float* possum = (float*)(num_pos + B);                      // B
    float* lossl  = possum + B;                                 // B
    float* acc    = lossl + B;                                  // [_, loss_c]

    init_k<<<1, 256, 0, stream>>>(num_pos, possum, lossl, acc);
    bp_k<<<B, 1024, 0, stream>>>(dbox, truths, forced_p);
    loss_k<<<dim3((P + ROWS_PER_BLOCK - 1) / ROWS_PER_BLOCK, B), 256, 0, stream>>>(
        loc_data, conf_data, dbox, truths, labels, forced_p,
        negce, num_pos, possum, lossl);
    mine_k<<<B, 1024, 0, stream>>>(negce, num_pos, possum, acc);
    final_k<<<1, 1, 0, stream>>>(acc, num_pos, lossl, out);
}